// Round 1
// baseline (73.141 us; speedup 1.0000x reference)
//
#include <hip/hip_runtime.h>

#define IN_DIM  16384
#define OUT_DIM 16384
#define BATCH   2048

// OP_COEFFS from the reference, row-major [16][4]
__device__ __constant__ float OPC[16][4] = {
    {0.f, 0.f, 0.f, 0.f}, {0.f, 0.f, 0.f, 1.f}, {0.f, 1.f, 0.f, -1.f}, {0.f, 1.f, 0.f, 0.f},
    {0.f, 0.f, 1.f, -1.f}, {0.f, 0.f, 1.f, 0.f}, {0.f, 1.f, 1.f, -2.f}, {0.f, 1.f, 1.f, -1.f},
    {1.f, -1.f, -1.f, 1.f}, {1.f, -1.f, -1.f, 2.f}, {1.f, 0.f, -1.f, 0.f}, {1.f, 0.f, -1.f, 1.f},
    {1.f, -1.f, 0.f, 0.f}, {1.f, -1.f, 0.f, 1.f}, {1.f, 0.f, 0.f, -1.f}, {1.f, 0.f, 0.f, 0.f}};

// Prep: per output column j, softmax(weights[j,0:16]) @ OP_COEFFS -> coef[j] (float4),
// and pack idx_a[j] | idx_b[j]<<16 (both < 16384 < 2^16).
__global__ __launch_bounds__(256) void prep_kernel(const float* __restrict__ w,
                                                   const int* __restrict__ ia,
                                                   const int* __restrict__ ib,
                                                   float4* __restrict__ coef,
                                                   unsigned* __restrict__ packed) {
    int j = blockIdx.x * 256 + threadIdx.x;
    if (j >= OUT_DIM) return;

    const float4* wr = (const float4*)(w + (size_t)j * 16);
    float wv[16];
    float4 w0 = wr[0], w1 = wr[1], w2 = wr[2], w3 = wr[3];
    wv[0] = w0.x; wv[1] = w0.y; wv[2] = w0.z; wv[3] = w0.w;
    wv[4] = w1.x; wv[5] = w1.y; wv[6] = w1.z; wv[7] = w1.w;
    wv[8] = w2.x; wv[9] = w2.y; wv[10] = w2.z; wv[11] = w2.w;
    wv[12] = w3.x; wv[13] = w3.y; wv[14] = w3.z; wv[15] = w3.w;

    float m = wv[0];
#pragma unroll
    for (int k = 1; k < 16; ++k) m = fmaxf(m, wv[k]);
    float s = 0.f;
#pragma unroll
    for (int k = 0; k < 16; ++k) { wv[k] = expf(wv[k] - m); s += wv[k]; }
    float inv = 1.f / s;

    float c0 = 0.f, c1 = 0.f, c2 = 0.f, c3 = 0.f;
#pragma unroll
    for (int k = 0; k < 16; ++k) {
        float p = wv[k];
        c0 = fmaf(p, OPC[k][0], c0);
        c1 = fmaf(p, OPC[k][1], c1);
        c2 = fmaf(p, OPC[k][2], c2);
        c3 = fmaf(p, OPC[k][3], c3);
    }
    coef[j] = make_float4(c0 * inv, c1 * inv, c2 * inv, c3 * inv);
    packed[j] = (unsigned)ia[j] | ((unsigned)ib[j] << 16);
}

// Main: one block per row of x. Stage the 64 KiB row in LDS, then the gather
// is a random 4B LDS read instead of a cache-line-dragging global gather.
__global__ __launch_bounds__(512, 4) void logic_kernel(const float* __restrict__ x,
                                                       const unsigned* __restrict__ packed,
                                                       const float4* __restrict__ coef,
                                                       float* __restrict__ out) {
    __shared__ float lds[IN_DIM];  // exactly 64 KiB -> 2 blocks/CU

    const int row = blockIdx.x;
    const float4* xr4 = (const float4*)(x + (size_t)row * IN_DIM);
    float4* lds4 = (float4*)lds;

#pragma unroll
    for (int k = threadIdx.x; k < IN_DIM / 4; k += 512) {
        lds4[k] = xr4[k];
    }
    __syncthreads();

    float* outr = out + (size_t)row * IN_DIM;

#pragma unroll
    for (int it = 0; it < IN_DIM / (512 * 4); ++it) {
        int j0 = (it * 512 + threadIdx.x) * 4;

        uint4 pi = *(const uint4*)(packed + j0);
        float4 c0 = coef[j0 + 0];
        float4 c1 = coef[j0 + 1];
        float4 c2 = coef[j0 + 2];
        float4 c3 = coef[j0 + 3];

        float4 o;
        {
            float a = lds[pi.x & 0xFFFFu], b = lds[pi.x >> 16];
            o.x = fmaf(a, fmaf(c0.w, b, c0.y), fmaf(c0.z, b, c0.x));
        }
        {
            float a = lds[pi.y & 0xFFFFu], b = lds[pi.y >> 16];
            o.y = fmaf(a, fmaf(c1.w, b, c1.y), fmaf(c1.z, b, c1.x));
        }
        {
            float a = lds[pi.z & 0xFFFFu], b = lds[pi.z >> 16];
            o.z = fmaf(a, fmaf(c2.w, b, c2.y), fmaf(c2.z, b, c2.x));
        }
        {
            float a = lds[pi.w & 0xFFFFu], b = lds[pi.w >> 16];
            o.w = fmaf(a, fmaf(c3.w, b, c3.y), fmaf(c3.z, b, c3.x));
        }
        *(float4*)(outr + j0) = o;
    }
}

extern "C" void kernel_launch(void* const* d_in, const int* in_sizes, int n_in,
                              void* d_out, int out_size, void* d_ws, size_t ws_size,
                              hipStream_t stream) {
    const float* x = (const float*)d_in[0];
    const int* ia = (const int*)d_in[1];
    const int* ib = (const int*)d_in[2];
    const float* w = (const float*)d_in[3];
    float* out = (float*)d_out;

    // ws layout: [0, 256 KiB) coef float4[OUT_DIM]; [256 KiB, 320 KiB) packed idx u32[OUT_DIM]
    float4* coef = (float4*)d_ws;
    unsigned* packed = (unsigned*)((char*)d_ws + (size_t)OUT_DIM * sizeof(float4));

    prep_kernel<<<OUT_DIM / 256, 256, 0, stream>>>(w, ia, ib, coef, packed);
    logic_kernel<<<BATCH, 512, 0, stream>>>(x, packed, coef, out);
}

// Round 3
// 70.860 us; speedup vs baseline: 1.0322x; 1.0322x over previous
//
#include <hip/hip_runtime.h>

#define IN_DIM  16384
#define OUT_DIM 16384
#define BATCH   2048
#define NBLK    256
#define RPB     (BATCH / NBLK)   // 8 rows per block
#define TPB     1024

typedef float f32x4 __attribute__((ext_vector_type(4)));

// OP_COEFFS from the reference, row-major [16][4]
__device__ __constant__ float OPC[16][4] = {
    {0.f, 0.f, 0.f, 0.f}, {0.f, 0.f, 0.f, 1.f}, {0.f, 1.f, 0.f, -1.f}, {0.f, 1.f, 0.f, 0.f},
    {0.f, 0.f, 1.f, -1.f}, {0.f, 0.f, 1.f, 0.f}, {0.f, 1.f, 1.f, -2.f}, {0.f, 1.f, 1.f, -1.f},
    {1.f, -1.f, -1.f, 1.f}, {1.f, -1.f, -1.f, 2.f}, {1.f, 0.f, -1.f, 0.f}, {1.f, 0.f, -1.f, 1.f},
    {1.f, -1.f, 0.f, 0.f}, {1.f, -1.f, 0.f, 1.f}, {1.f, 0.f, 0.f, -1.f}, {1.f, 0.f, 0.f, 0.f}};

// Prep: per output column j, softmax(weights[j,0:16]) @ OP_COEFFS -> coef[j] (float4),
// and pack idx_a[j] | idx_b[j]<<16 (both < 16384 < 2^16).
__global__ __launch_bounds__(256) void prep_kernel(const float* __restrict__ w,
                                                   const int* __restrict__ ia,
                                                   const int* __restrict__ ib,
                                                   float4* __restrict__ coef,
                                                   unsigned* __restrict__ packed) {
    int j = blockIdx.x * 256 + threadIdx.x;
    if (j >= OUT_DIM) return;

    const float4* wr = (const float4*)(w + (size_t)j * 16);
    float wv[16];
    float4 w0 = wr[0], w1 = wr[1], w2 = wr[2], w3 = wr[3];
    wv[0] = w0.x; wv[1] = w0.y; wv[2] = w0.z; wv[3] = w0.w;
    wv[4] = w1.x; wv[5] = w1.y; wv[6] = w1.z; wv[7] = w1.w;
    wv[8] = w2.x; wv[9] = w2.y; wv[10] = w2.z; wv[11] = w2.w;
    wv[12] = w3.x; wv[13] = w3.y; wv[14] = w3.z; wv[15] = w3.w;

    float m = wv[0];
#pragma unroll
    for (int k = 1; k < 16; ++k) m = fmaxf(m, wv[k]);
    float s = 0.f;
#pragma unroll
    for (int k = 0; k < 16; ++k) { wv[k] = expf(wv[k] - m); s += wv[k]; }
    float inv = 1.f / s;

    float c0 = 0.f, c1 = 0.f, c2 = 0.f, c3 = 0.f;
#pragma unroll
    for (int k = 0; k < 16; ++k) {
        float p = wv[k];
        c0 = fmaf(p, OPC[k][0], c0);
        c1 = fmaf(p, OPC[k][1], c1);
        c2 = fmaf(p, OPC[k][2], c2);
        c3 = fmaf(p, OPC[k][3], c3);
    }
    coef[j] = make_float4(c0 * inv, c1 * inv, c2 * inv, c3 * inv);
    packed[j] = (unsigned)ia[j] | ((unsigned)ib[j] << 16);
}

// One block owns 8 consecutive rows. T14 async-STAGE split double buffer:
//   barrier (lgkm drain: buffer `cur` fully ds_written by all waves)
//   issue global loads of row r+1 into regs   <- HBM latency hides under compute
//   compute row r from lds[cur]
//   ds_write regs -> lds[cur^1]               <- protected by next barrier's lgkm drain
// All ordering relies only on standard ds_write/lgkmcnt barrier semantics.
__global__ __launch_bounds__(TPB, 1) void logic_kernel(const float* __restrict__ x,
                                                       const unsigned* __restrict__ packed,
                                                       const float4* __restrict__ coef,
                                                       float* __restrict__ out) {
    __shared__ float lds[2][IN_DIM];  // 128 KiB -> 1 block/CU, 16 waves/CU

    const int tid = threadIdx.x;
    const int row0 = blockIdx.x * RPB;

    // Prologue: stage row0 into lds[0] (reg round-trip; latency exposed only once)
    {
        const float4* src = (const float4*)(x + (size_t)row0 * IN_DIM);
        float4* dst = (float4*)lds[0];
#pragma unroll
        for (int k = 0; k < IN_DIM / (TPB * 4); ++k)  // 4 iterations
            dst[k * TPB + tid] = src[k * TPB + tid];
    }

    for (int r = 0; r < RPB; ++r) {
        const int cur = r & 1;
        __syncthreads();  // lgkmcnt(0) drain: lds[cur] complete across all waves

        const bool pf = (r + 1 < RPB);
        float4 t0 = {}, t1 = {}, t2 = {}, t3 = {};
        if (pf) {
            const float4* src = (const float4*)(x + (size_t)(row0 + r + 1) * IN_DIM);
            t0 = src[0 * TPB + tid];
            t1 = src[1 * TPB + tid];
            t2 = src[2 * TPB + tid];
            t3 = src[3 * TPB + tid];
        }
        __builtin_amdgcn_sched_barrier(0);  // pin the prefetch loads before compute

        const float* buf = lds[cur];
        float* outr = out + (size_t)(row0 + r) * IN_DIM;

#pragma unroll
        for (int it = 0; it < OUT_DIM / (TPB * 4); ++it) {  // 4 iterations
            const int j0 = (it * TPB + tid) * 4;

            const uint4 pi = *(const uint4*)(packed + j0);
            const float4 c0 = coef[j0 + 0];
            const float4 c1 = coef[j0 + 1];
            const float4 c2 = coef[j0 + 2];
            const float4 c3 = coef[j0 + 3];

            f32x4 o;
            {
                float a = buf[pi.x & 0xFFFFu], b = buf[pi.x >> 16];
                o.x = fmaf(a, fmaf(c0.w, b, c0.y), fmaf(c0.z, b, c0.x));
            }
            {
                float a = buf[pi.y & 0xFFFFu], b = buf[pi.y >> 16];
                o.y = fmaf(a, fmaf(c1.w, b, c1.y), fmaf(c1.z, b, c1.x));
            }
            {
                float a = buf[pi.z & 0xFFFFu], b = buf[pi.z >> 16];
                o.z = fmaf(a, fmaf(c2.w, b, c2.y), fmaf(c2.z, b, c2.x));
            }
            {
                float a = buf[pi.w & 0xFFFFu], b = buf[pi.w >> 16];
                o.w = fmaf(a, fmaf(c3.w, b, c3.y), fmaf(c3.z, b, c3.x));
            }
            __builtin_nontemporal_store(o, (f32x4*)(outr + j0));
        }

        if (pf) {
            float4* dst = (float4*)lds[cur ^ 1];
            dst[0 * TPB + tid] = t0;
            dst[1 * TPB + tid] = t1;
            dst[2 * TPB + tid] = t2;
            dst[3 * TPB + tid] = t3;
        }
    }
}

extern "C" void kernel_launch(void* const* d_in, const int* in_sizes, int n_in,
                              void* d_out, int out_size, void* d_ws, size_t ws_size,
                              hipStream_t stream) {
    const float* x = (const float*)d_in[0];
    const int* ia = (const int*)d_in[1];
    const int* ib = (const int*)d_in[2];
    const float* w = (const float*)d_in[3];
    float* out = (float*)d_out;

    // ws layout: [0, 256 KiB) coef float4[OUT_DIM]; [256 KiB, 320 KiB) packed idx u32[OUT_DIM]
    float4* coef = (float4*)d_ws;
    unsigned* packed = (unsigned*)((char*)d_ws + (size_t)OUT_DIM * sizeof(float4));

    prep_kernel<<<OUT_DIM / 256, 256, 0, stream>>>(w, ia, ib, coef, packed);
    logic_kernel<<<NBLK, TPB, 0, stream>>>(x, packed, coef, out);
}